// Round 5
// baseline (2180.220 us; speedup 1.0000x reference)
//
#include <hip/hip_runtime.h>
#include <hip/hip_bf16.h>

typedef __attribute__((ext_vector_type(8))) short bf16x8;
typedef __attribute__((ext_vector_type(4))) float f32x4;

#define NBATCH 4096
#define SEQT 181
#define NFEAT 12
#define HDIM 128
#define ROWS 16
#define LSTR 136              // padded bf16 row stride for activations (2-way conflict = free)
#define OUTSTRIDE (SEQT*NFEAT)

// d_ws layout (same as R1..R4):
#define WFRAG_ELEMS 262144
#define WOUT_ELEMS  4096
#define BIAS_F32OFF (532480/4)
#define BOUT_F32OFF (536576/4)

// LDS byte offsets: [0,131072) weight tail frags; act 6 bufs; bias f32; bout
#define ACT_OFF  131072
#define BIAS_OFF 157184
#define BOUT_OFF 161280
#define SMEM_BYTES 161344

__device__ __forceinline__ float fsig(float x) {
  return __builtin_amdgcn_rcpf(1.0f + __builtin_amdgcn_exp2f(-1.442695041f * x));
}
__device__ __forceinline__ float ftanh(float x) {
  float e = __builtin_amdgcn_exp2f(-2.885390082f * x);   // = exp(-2x)
  return __builtin_fmaf(2.0f, __builtin_amdgcn_rcpf(1.0f + e), -1.0f);
}
__device__ __forceinline__ unsigned short f2bf(float x) {
  __hip_bfloat16 h = __float2bfloat16(x);
  return __builtin_bit_cast(unsigned short, h);
}

// ---------------- setup: repack weights into MFMA fragment order (bf16) ----------------
__global__ void setup_kernel(const float* __restrict__ Wih0, const float* __restrict__ Whh0,
                             const float* __restrict__ bih0, const float* __restrict__ bhh0,
                             const float* __restrict__ Wih1, const float* __restrict__ Whh1,
                             const float* __restrict__ bih1, const float* __restrict__ bhh1,
                             const float* __restrict__ Wo,   const float* __restrict__ bo,
                             unsigned short* __restrict__ ws)
{
  int idx = blockIdx.x * blockDim.x + threadIdx.x;
  if (idx < WFRAG_ELEMS) {
    // A-frag (weights): lane&15 = gate-dim, k=(lane>>4)*8+e over [x(128)|h(128)]
    int e = idx & 7, lane = (idx >> 3) & 63, s = (idx >> 9) & 7, g = (idx >> 12) & 3,
        w = (idx >> 14) & 7, l = idx >> 17;
    int row = g * 128 + w * 16 + (lane & 15);
    int k   = s * 32 + (lane >> 4) * 8 + e;
    const float* Wih = l ? Wih1 : Wih0;
    const float* Whh = l ? Whh1 : Whh0;
    float v = (k < HDIM) ? Wih[row * HDIM + k] : Whh[row * HDIM + (k - HDIM)];
    ws[idx] = f2bf(v);
  } else if (idx < WFRAG_ELEMS + WOUT_ELEMS) {
    int i2 = idx - WFRAG_ELEMS;
    int e = i2 & 7, lane = (i2 >> 3) & 63, s = i2 >> 9;
    int c = lane & 15;
    int k = s * 32 + (lane >> 4) * 8 + e;           // k over [z0(128) | z1(128)]
    float v = (c < NFEAT) ? Wo[c * 256 + k] : 0.0f;
    ws[idx] = f2bf(v);
  } else if (idx < WFRAG_ELEMS + WOUT_ELEMS + 1024) {
    int i3 = idx - (WFRAG_ELEMS + WOUT_ELEMS);
    int l = i3 >> 9, r = i3 & 511;
    float v = l ? (bih1[r] + bhh1[r]) : (bih0[r] + bhh0[r]);
    reinterpret_cast<float*>(ws)[BIAS_F32OFF + i3] = v;
  } else if (idx < WFRAG_ELEMS + WOUT_ELEMS + 1024 + 16) {
    int i4 = idx - (WFRAG_ELEMS + WOUT_ELEMS + 1024);
    reinterpret_cast<float*>(ws)[BOUT_F32OFF + i4] = (i4 < NFEAT) ? bo[i4] : 0.0f;
  }
}

// ---------------- main: 256 blocks x 512 threads; weights pinned in AGPRs + LDS ----------------
// R5: pin weight frags with "+a" (AGPR class). gfx950 MFMA operands are AV-class
// (agpr-or-vgpr), so AGPR-resident A operands feed v_mfma directly with no copies.
// Evidence AGPR pool is budgeted separately from the 128-VGPR arch budget: m97-style
// kernels allocate 164 VGPR + 64 AGPR and still run 3 blocks/CU.
__global__ void __launch_bounds__(512) __attribute__((amdgpu_waves_per_eu(2, 2)))
lstm_kernel(
    const float* __restrict__ ench, const float* __restrict__ encc,
    const unsigned short* __restrict__ wfrag, const unsigned short* __restrict__ woutf,
    const float* __restrict__ biasc, const float* __restrict__ boutc,
    float* __restrict__ out)
{
  __shared__ __align__(16) unsigned char smem[SMEM_BYTES];
  bf16x8* wlds = reinterpret_cast<bf16x8*>(smem);
  unsigned short* act = reinterpret_cast<unsigned short*>(smem + ACT_OFF);

  const int tid  = threadIdx.x;
  const int wave = tid >> 6, lane = tid & 63;
  const int col  = lane & 15, lg = lane >> 4;
  const int n0   = blockIdx.x * ROWS;
  const int dbase = wave * 16 + lg * 4;

  // ---- persistent weight fragments: s=0..5 pinned in AGPRs, s=6..7 in LDS ----
  bf16x8 wreg[2][4][6];
  const bf16x8* wfv = reinterpret_cast<const bf16x8*>(wfrag);
  #pragma unroll
  for (int l = 0; l < 2; ++l)
    #pragma unroll
    for (int g = 0; g < 4; ++g) {
      #pragma unroll
      for (int s = 0; s < 6; ++s)
        wreg[l][g][s] = wfv[(size_t)((((l * 8 + wave) * 4 + g) * 8) + s) * 64 + lane];
      #pragma unroll
      for (int si = 0; si < 2; ++si)
        wlds[(((wave * 2 + l) * 4 + g) * 2 + si) * 64 + lane] =
            wfv[(size_t)((((l * 8 + wave) * 4 + g) * 8) + 6 + si) * 64 + lane];
    }
  // pin into AGPR class: opaque (no remat) + lives in the accumulator file,
  // off the arch-VGPR budget that R2-R4 showed is stuck at 128.
  #pragma unroll
  for (int l = 0; l < 2; ++l)
    #pragma unroll
    for (int g = 0; g < 4; ++g)
      #pragma unroll
      for (int s = 0; s < 6; ++s) {
        f32x4 tmp = __builtin_bit_cast(f32x4, wreg[l][g][s]);
        asm volatile("" : "+a"(tmp));
        wreg[l][g][s] = __builtin_bit_cast(bf16x8, tmp);
      }

  // zero x-ping buffers 0,1 (dec_in0 = 0)
  for (int i = tid; i < 2 * ROWS * LSTR; i += 512) act[i] = 0;
  // initial h layer0 -> buf5
  for (int i = tid; i < ROWS * HDIM; i += 512) {
    int r = i >> 7, d = i & (HDIM - 1);
    act[(5 * ROWS + r) * LSTR + d] = f2bf(ench[(n0 + r) * HDIM + d]);
  }
  // bias -> LDS  (256 entries of f32x4: [l][g][wave][lg])
  for (int i = tid; i < 256; i += 512) {
    int l = i >> 7, g = (i >> 5) & 3, w = (i >> 2) & 7, q = i & 3;
    f32x4 b = *reinterpret_cast<const f32x4*>(&biasc[l * 512 + g * 128 + w * 16 + q * 4]);
    *reinterpret_cast<f32x4*>(smem + BIAS_OFF + i * 16) = b;
  }
  if (tid < 16) reinterpret_cast<float*>(smem + BOUT_OFF)[tid] = boutc[tid];
  // c-state: lane holds batch n0+col, dims dbase..dbase+3
  f32x4 c0 = *reinterpret_cast<const f32x4*>(&encc[(size_t)(n0 + col) * HDIM + dbase]);
  f32x4 c1 = *reinterpret_cast<const f32x4*>(&encc[(size_t)(NBATCH + n0 + col) * HDIM + dbase]);
  __syncthreads();

  const int aoffl = col * LSTR + lg * 8;

  auto load4 = [&](int buf, bf16x8 (&a)[4]) {
    const unsigned short* p = act + buf * (ROWS * LSTR) + aoffl;
    #pragma unroll
    for (int s = 0; s < 4; ++s)
      a[s] = *reinterpret_cast<const bf16x8*>(&p[s * 32]);
  };
  auto load4_e1 = [&](bf16x8 (&a)[4]) {      // t=0 layer-1 h straight from global (f32->bf16)
    const float* p = ench + (size_t)(NBATCH + n0 + col) * HDIM + lg * 8;
    #pragma unroll
    for (int s = 0; s < 4; ++s) {
      f32x4 u = *reinterpret_cast<const f32x4*>(&p[s * 32]);
      f32x4 v = *reinterpret_cast<const f32x4*>(&p[s * 32 + 4]);
      bf16x8 r;
      r[0] = (short)f2bf(u[0]); r[1] = (short)f2bf(u[1]);
      r[2] = (short)f2bf(u[2]); r[3] = (short)f2bf(u[3]);
      r[4] = (short)f2bf(v[0]); r[5] = (short)f2bf(v[1]);
      r[6] = (short)f2bf(v[2]); r[7] = (short)f2bf(v[3]);
      a[s] = r;
    }
  };

  auto run_cell = [&](const bf16x8 (&xa)[4], const bf16x8 (&ha)[4], int ob,
                      const bf16x8 (&wr)[4][6], int lb, int bl, f32x4& c) {
    f32x4 acc[4];
    #pragma unroll
    for (int g = 0; g < 4; ++g)
      acc[g] = *reinterpret_cast<const f32x4*>(
          smem + BIAS_OFF + (size_t)(bl * 128 + g * 32 + wave * 4 + lg) * 16);
    #pragma unroll
    for (int s = 0; s < 4; ++s)                        // k = x-half (AGPR weights)
      #pragma unroll
      for (int g = 0; g < 4; ++g)
        acc[g] = __builtin_amdgcn_mfma_f32_16x16x32_bf16(wr[g][s], xa[s], acc[g], 0, 0, 0);
    #pragma unroll
    for (int s = 0; s < 2; ++s)                        // k = h-half, AGPR weights
      #pragma unroll
      for (int g = 0; g < 4; ++g)
        acc[g] = __builtin_amdgcn_mfma_f32_16x16x32_bf16(wr[g][4 + s], ha[s], acc[g], 0, 0, 0);
    #pragma unroll
    for (int si = 0; si < 2; ++si)                     // k = h-half tail, LDS weights
      #pragma unroll
      for (int g = 0; g < 4; ++g) {
        bf16x8 wf = wlds[(lb + g * 2 + si) * 64 + lane];
        acc[g] = __builtin_amdgcn_mfma_f32_16x16x32_bf16(wf, ha[2 + si], acc[g], 0, 0, 0);
      }
    // gates: i,f,g,o ; lane: batch col, dims dbase..dbase+3
    unsigned int p0, p1;
    {
      float cn0 = fsig(acc[1][0]) * c[0] + fsig(acc[0][0]) * ftanh(acc[2][0]);
      float cn1 = fsig(acc[1][1]) * c[1] + fsig(acc[0][1]) * ftanh(acc[2][1]);
      float cn2 = fsig(acc[1][2]) * c[2] + fsig(acc[0][2]) * ftanh(acc[2][2]);
      float cn3 = fsig(acc[1][3]) * c[3] + fsig(acc[0][3]) * ftanh(acc[2][3]);
      c[0] = cn0; c[1] = cn1; c[2] = cn2; c[3] = cn3;
      unsigned int h0 = f2bf(fsig(acc[3][0]) * ftanh(cn0));
      unsigned int h1 = f2bf(fsig(acc[3][1]) * ftanh(cn1));
      unsigned int h2 = f2bf(fsig(acc[3][2]) * ftanh(cn2));
      unsigned int h3 = f2bf(fsig(acc[3][3]) * ftanh(cn3));
      p0 = h0 | (h1 << 16); p1 = h2 | (h3 << 16);
    }
    uint2* op = reinterpret_cast<uint2*>(act + ob * (ROWS * LSTR) + col * LSTR + dbase);
    *op = make_uint2(p0, p1);
    __syncthreads();
  };

  const int lb0 = (wave * 2 + 0) * 8;
  const int lb1 = (wave * 2 + 1) * 8;
  const bf16x8* wov = reinterpret_cast<const bf16x8*>(woutf);

  bf16x8 xa[4], ha[4];
  for (int t = 0; t < SEQT; ++t) {
    const int xA = (t & 1) ? 2 : 0, xB = xA + 1;
    const int zA = (t & 1) ? 0 : 2, zB = zA + 1;
    load4(xA, xa); load4(5, ha);
    run_cell(xa, ha, 4, wreg[0], lb0, 0, c0);          // L0 t0
    load4(xB, xa); load4(4, ha);
    run_cell(xa, ha, 5, wreg[0], lb0, 0, c0);          // L0 t1
    load4(4, xa);
    if (t == 0) load4_e1(ha); else load4(xB, ha);
    run_cell(xa, ha, zA, wreg[1], lb1, 1, c1);         // L1 t0
    load4(5, xa); load4(zA, ha);
    run_cell(xa, ha, zB, wreg[1], lb1, 1, c1);         // L1 t1
    if (wave == 0) {                                   // output projection
      bf16x8 za[4], zb[4];
      load4(zA, za); load4(zB, zb);
      f32x4 po = *reinterpret_cast<const f32x4*>(smem + BOUT_OFF + lg * 16);
      #pragma unroll
      for (int s = 0; s < 4; ++s)
        po = __builtin_amdgcn_mfma_f32_16x16x32_bf16(wov[s * 64 + lane], za[s], po, 0, 0, 0);
      #pragma unroll
      for (int s = 0; s < 4; ++s)
        po = __builtin_amdgcn_mfma_f32_16x16x32_bf16(wov[(4 + s) * 64 + lane], zb[s], po, 0, 0, 0);
      if (lg < 3) {
        f32x4 r;
        r[0] = fsig(po[0]); r[1] = fsig(po[1]); r[2] = fsig(po[2]); r[3] = fsig(po[3]);
        *reinterpret_cast<f32x4*>(&out[(size_t)(n0 + col) * OUTSTRIDE + t * NFEAT + lg * 4]) = r;
      }
    }
  }
}

extern "C" void kernel_launch(void* const* d_in, const int* in_sizes, int n_in,
                              void* d_out, int out_size, void* d_ws, size_t ws_size,
                              hipStream_t stream) {
  const float* ench = (const float*)d_in[0];
  const float* encc = (const float*)d_in[1];
  const float* Wih0 = (const float*)d_in[2];
  const float* Whh0 = (const float*)d_in[3];
  const float* bih0 = (const float*)d_in[4];
  const float* bhh0 = (const float*)d_in[5];
  const float* Wih1 = (const float*)d_in[6];
  const float* Whh1 = (const float*)d_in[7];
  const float* bih1 = (const float*)d_in[8];
  const float* bhh1 = (const float*)d_in[9];
  const float* Wo   = (const float*)d_in[10];
  const float* bo   = (const float*)d_in[11];
  unsigned short* ws = (unsigned short*)d_ws;

  int total = WFRAG_ELEMS + WOUT_ELEMS + 1024 + 16;
  int blocks = (total + 511) / 512;
  hipLaunchKernelGGL(setup_kernel, dim3(blocks), dim3(512), 0, stream,
                     Wih0, Whh0, bih0, bhh0, Wih1, Whh1, bih1, bhh1, Wo, bo, ws);

  const unsigned short* wfrag = ws;
  const unsigned short* woutf = ws + WFRAG_ELEMS;
  const float* biasc = reinterpret_cast<const float*>(ws) + BIAS_F32OFF;
  const float* boutc = reinterpret_cast<const float*>(ws) + BOUT_F32OFF;

  hipLaunchKernelGGL(lstm_kernel, dim3(NBATCH / ROWS), dim3(512), 0, stream,
                     ench, encc, wfrag, woutf, biasc, boutc, (float*)d_out);
}

// Round 8
// 898.832 us; speedup vs baseline: 2.4256x; 2.4256x over previous
//
#include <hip/hip_runtime.h>
#include <hip/hip_bf16.h>

typedef __attribute__((ext_vector_type(8))) short bf16x8;
typedef __attribute__((ext_vector_type(4))) float f32x4;

#define NBATCH 4096
#define SEQT 181
#define NFEAT 12
#define HDIM 128
#define ROWS 16
#define LSTR 136              // padded bf16 row stride for activations
#define OUTSTRIDE (SEQT*NFEAT)

// d_ws layout (same as R1..R7):
#define WFRAG_ELEMS 262144
#define WOUT_ELEMS  4096
#define BIAS_F32OFF (532480/4)
#define BOUT_F32OFF (536576/4)

// LDS byte offsets: [0,131072) weight tail frags (s=6,7); act 6 bufs; bias f32; bout
#define ACT_OFF  131072
#define BIAS_OFF 157184
#define BOUT_OFF 161280
#define SMEM_BYTES 161344

__device__ __forceinline__ float fsig(float x) {
  return __builtin_amdgcn_rcpf(1.0f + __builtin_amdgcn_exp2f(-1.442695041f * x));
}
__device__ __forceinline__ float ftanh(float x) {
  float e = __builtin_amdgcn_exp2f(-2.885390082f * x);   // = exp(-2x)
  return __builtin_fmaf(2.0f, __builtin_amdgcn_rcpf(1.0f + e), -1.0f);
}
__device__ __forceinline__ unsigned short f2bf(float x) {
  __hip_bfloat16 h = __float2bfloat16(x);
  return __builtin_bit_cast(unsigned short, h);
}

// ---------------- setup: repack weights into MFMA fragment order (bf16) ----------------
__global__ void setup_kernel(const float* __restrict__ Wih0, const float* __restrict__ Whh0,
                             const float* __restrict__ bih0, const float* __restrict__ bhh0,
                             const float* __restrict__ Wih1, const float* __restrict__ Whh1,
                             const float* __restrict__ bih1, const float* __restrict__ bhh1,
                             const float* __restrict__ Wo,   const float* __restrict__ bo,
                             unsigned short* __restrict__ ws)
{
  int idx = blockIdx.x * blockDim.x + threadIdx.x;
  if (idx < WFRAG_ELEMS) {
    // A-frag (weights): lane&15 = gate-dim, k=(lane>>4)*8+e over [x(128)|h(128)]
    int e = idx & 7, lane = (idx >> 3) & 63, s = (idx >> 9) & 7, g = (idx >> 12) & 3,
        w = (idx >> 14) & 7, l = idx >> 17;
    int row = g * 128 + w * 16 + (lane & 15);
    int k   = s * 32 + (lane >> 4) * 8 + e;
    const float* Wih = l ? Wih1 : Wih0;
    const float* Whh = l ? Whh1 : Whh0;
    float v = (k < HDIM) ? Wih[row * HDIM + k] : Whh[row * HDIM + (k - HDIM)];
    ws[idx] = f2bf(v);
  } else if (idx < WFRAG_ELEMS + WOUT_ELEMS) {
    int i2 = idx - WFRAG_ELEMS;
    int e = i2 & 7, lane = (i2 >> 3) & 63, s = i2 >> 9;
    int c = lane & 15;
    int k = s * 32 + (lane >> 4) * 8 + e;           // k over [z0(128) | z1(128)]
    float v = (c < NFEAT) ? Wo[c * 256 + k] : 0.0f;
    ws[idx] = f2bf(v);
  } else if (idx < WFRAG_ELEMS + WOUT_ELEMS + 1024) {
    int i3 = idx - (WFRAG_ELEMS + WOUT_ELEMS);
    int l = i3 >> 9, r = i3 & 511;
    float v = l ? (bih1[r] + bhh1[r]) : (bih0[r] + bhh0[r]);
    reinterpret_cast<float*>(ws)[BIAS_F32OFF + i3] = v;
  } else if (idx < WFRAG_ELEMS + WOUT_ELEMS + 1024 + 16) {
    int i4 = idx - (WFRAG_ELEMS + WOUT_ELEMS + 1024);
    reinterpret_cast<float*>(ws)[BOUT_F32OFF + i4] = (i4 < NFEAT) ? bo[i4] : 0.0f;
  }
}

// ---------------- main: 256 blocks x 512 threads ------------------------------------
// R8 theory: R2-R5 spills were caused by a register-pressure SPIKE at init (48
// clustered global loads), not by a hard 128 budget (LDS 161KB already implies
// 2 waves/EU -> 256-reg budget). Fix: load+pin weight frags in chunks of 6 with
// sched_barrier(0) fences so transient pressure stays ~210; stream B-fragments
// in the cells to keep steady-state arch demand ~45 on top of the 192 pinned.
__global__ void
__attribute__((amdgpu_flat_work_group_size(512, 512), amdgpu_waves_per_eu(2, 2)))
lstm_kernel(
    const float* __restrict__ ench, const float* __restrict__ encc,
    const unsigned short* __restrict__ wfrag, const unsigned short* __restrict__ woutf,
    const float* __restrict__ biasc, const float* __restrict__ boutc,
    float* __restrict__ out)
{
  __shared__ __align__(16) unsigned char smem[SMEM_BYTES];
  bf16x8* wlds = reinterpret_cast<bf16x8*>(smem);
  unsigned short* act = reinterpret_cast<unsigned short*>(smem + ACT_OFF);

  const int tid  = threadIdx.x;
  const int wave = tid >> 6, lane = tid & 63;
  const int col  = lane & 15, lg = lane >> 4;
  const int n0   = blockIdx.x * ROWS;
  const int dbase = wave * 16 + lg * 4;

  const bf16x8* wfv = reinterpret_cast<const bf16x8*>(wfrag);

  // ---- persistent weight fragments: s=0..5 in registers (pinned chunk-by-chunk,
  //      fenced so the scheduler can't cluster all 48 loads into one pressure spike)
  bf16x8 wreg[2][4][6];
  #pragma unroll
  for (int l = 0; l < 2; ++l)
    #pragma unroll
    for (int g = 0; g < 4; ++g) {
      #pragma unroll
      for (int s = 0; s < 6; ++s)
        wreg[l][g][s] = wfv[(size_t)((((l * 8 + wave) * 4 + g) * 8) + s) * 64 + lane];
      #pragma unroll
      for (int s = 0; s < 6; ++s) {
        f32x4 t_ = __builtin_bit_cast(f32x4, wreg[l][g][s]);
        asm volatile("" : "+v"(t_));            // opaque: no remat, value must stay live
        wreg[l][g][s] = __builtin_bit_cast(bf16x8, t_);
      }
      __builtin_amdgcn_sched_barrier(0);        // fence: next chunk can't be hoisted up
    }

  // ---- s=6..7 fragments -> LDS (16/wave, 128 KiB total) ----
  #pragma unroll
  for (int l = 0; l < 2; ++l)
    #pragma unroll
    for (int g = 0; g < 4; ++g)
      #pragma unroll
      for (int si = 0; si < 2; ++si)
        wlds[(((wave * 2 + l) * 4 + g) * 2 + si) * 64 + lane] =
            wfv[(size_t)((((l * 8 + wave) * 4 + g) * 8) + 6 + si) * 64 + lane];

  // zero x-ping buffers 0,1 (dec_in0 = 0)
  for (int i = tid; i < 2 * ROWS * LSTR; i += 512) act[i] = 0;
  // initial h layer0 -> buf5 ; initial h layer1 -> buf3 (read once by L1t0 at t=0,
  // then overwritten by L1t1(t=0) which runs after that read -- no race)
  for (int i = tid; i < ROWS * HDIM; i += 512) {
    int r = i >> 7, d = i & (HDIM - 1);
    act[(5 * ROWS + r) * LSTR + d] = f2bf(ench[(n0 + r) * HDIM + d]);
    act[(3 * ROWS + r) * LSTR + d] = f2bf(ench[(size_t)(NBATCH + n0 + r) * HDIM + d]);
  }
  // bias -> LDS  (256 entries of f32x4: [l][g][wave][lg])
  for (int i = tid; i < 256; i += 512) {
    int l = i >> 7, g = (i >> 5) & 3, w = (i >> 2) & 7, q = i & 3;
    f32x4 b = *reinterpret_cast<const f32x4*>(&biasc[l * 512 + g * 128 + w * 16 + q * 4]);
    *reinterpret_cast<f32x4*>(smem + BIAS_OFF + i * 16) = b;
  }
  if (tid < 16) reinterpret_cast<float*>(smem + BOUT_OFF)[tid] = boutc[tid];
  // c-state: lane holds batch n0+col, dims dbase..dbase+3
  f32x4 c0 = *reinterpret_cast<const f32x4*>(&encc[(size_t)(n0 + col) * HDIM + dbase]);
  f32x4 c1 = *reinterpret_cast<const f32x4*>(&encc[(size_t)(NBATCH + n0 + col) * HDIM + dbase]);
  __syncthreads();

  const int aoffl = col * LSTR + lg * 8;

  auto ldb = [&](int bl, int g) -> f32x4 {
    return *reinterpret_cast<const f32x4*>(
        smem + BIAS_OFF + (size_t)(bl * 128 + g * 32 + wave * 4 + lg) * 16);
  };

  // streamed cell: one B-fragment ds_read at a time -> 4 MFMAs; keeps the
  // steady-state arch-VGPR working set ~45 on top of the 192 pinned weights.
  auto cell = [&](int xb, int hb, int ob, const bf16x8 (&wr)[4][6], int lb, int bl, f32x4& c) {
    const unsigned short* xp = act + xb * (ROWS * LSTR) + aoffl;
    const unsigned short* hp = act + hb * (ROWS * LSTR) + aoffl;
    f32x4 acc0 = ldb(bl, 0), acc1 = ldb(bl, 1), acc2 = ldb(bl, 2), acc3 = ldb(bl, 3);
    #pragma unroll
    for (int s = 0; s < 4; ++s) {                       // k = x-half (reg weights)
      bf16x8 b = *reinterpret_cast<const bf16x8*>(&xp[s * 32]);
      acc0 = __builtin_amdgcn_mfma_f32_16x16x32_bf16(wr[0][s], b, acc0, 0, 0, 0);
      acc1 = __builtin_amdgcn_mfma_f32_16x16x32_bf16(wr[1][s], b, acc1, 0, 0, 0);
      acc2 = __builtin_amdgcn_mfma_f32_16x16x32_bf16(wr[2][s], b, acc2, 0, 0, 0);
      acc3 = __builtin_amdgcn_mfma_f32_16x16x32_bf16(wr[3][s], b, acc3, 0, 0, 0);
    }
    #pragma unroll
    for (int s = 0; s < 2; ++s) {                       // k = h-half, reg weights
      bf16x8 b = *reinterpret_cast<const bf16x8*>(&hp[s * 32]);
      acc0 = __builtin_amdgcn_mfma_f32_16x16x32_bf16(wr[0][4 + s], b, acc0, 0, 0, 0);
      acc1 = __builtin_amdgcn_mfma_f32_16x16x32_bf16(wr[1][4 + s], b, acc1, 0, 0, 0);
      acc2 = __builtin_amdgcn_mfma_f32_16x16x32_bf16(wr[2][4 + s], b, acc2, 0, 0, 0);
      acc3 = __builtin_amdgcn_mfma_f32_16x16x32_bf16(wr[3][4 + s], b, acc3, 0, 0, 0);
    }
    #pragma unroll
    for (int si = 0; si < 2; ++si) {                    // k = h-half tail, LDS weights
      bf16x8 b = *reinterpret_cast<const bf16x8*>(&hp[(2 + si) * 32]);
      bf16x8 w0 = wlds[(lb + 0 * 2 + si) * 64 + lane];
      bf16x8 w1 = wlds[(lb + 1 * 2 + si) * 64 + lane];
      bf16x8 w2 = wlds[(lb + 2 * 2 + si) * 64 + lane];
      bf16x8 w3 = wlds[(lb + 3 * 2 + si) * 64 + lane];
      acc0 = __builtin_amdgcn_mfma_f32_16x16x32_bf16(w0, b, acc0, 0, 0, 0);
      acc1 = __builtin_amdgcn_mfma_f32_16x16x32_bf16(w1, b, acc1, 0, 0, 0);
      acc2 = __builtin_amdgcn_mfma_f32_16x16x32_bf16(w2, b, acc2, 0, 0, 0);
      acc3 = __builtin_amdgcn_mfma_f32_16x16x32_bf16(w3, b, acc3, 0, 0, 0);
    }
    // gates: i,f,g,o ; lane: batch col, dims dbase..dbase+3
    float cn0 = fsig(acc1[0]) * c[0] + fsig(acc0[0]) * ftanh(acc2[0]);
    float cn1 = fsig(acc1[1]) * c[1] + fsig(acc0[1]) * ftanh(acc2[1]);
    float cn2 = fsig(acc1[2]) * c[2] + fsig(acc0[2]) * ftanh(acc2[2]);
    float cn3 = fsig(acc1[3]) * c[3] + fsig(acc0[3]) * ftanh(acc2[3]);
    c[0] = cn0; c[1] = cn1; c[2] = cn2; c[3] = cn3;
    unsigned int h0 = f2bf(fsig(acc3[0]) * ftanh(cn0));
    unsigned int h1 = f2bf(fsig(acc3[1]) * ftanh(cn1));
    unsigned int h2 = f2bf(fsig(acc3[2]) * ftanh(cn2));
    unsigned int h3 = f2bf(fsig(acc3[3]) * ftanh(cn3));
    uint2* op = reinterpret_cast<uint2*>(act + ob * (ROWS * LSTR) + col * LSTR + dbase);
    *op = make_uint2(h0 | (h1 << 16), h2 | (h3 << 16));
    __syncthreads();
  };

  const int lb0 = (wave * 2 + 0) * 8;
  const int lb1 = (wave * 2 + 1) * 8;
  const bf16x8* wov = reinterpret_cast<const bf16x8*>(woutf);

  for (int t = 0; t < SEQT; ++t) {
    const int xA = (t & 1) ? 2 : 0, xB = xA + 1;
    const int zA = (t & 1) ? 0 : 2, zB = zA + 1;
    cell(xA, 5, 4, wreg[0], lb0, 0, c0);               // L0 t0
    cell(xB, 4, 5, wreg[0], lb0, 0, c0);               // L0 t1
    cell(4, (t == 0) ? 3 : xB, zA, wreg[1], lb1, 1, c1); // L1 t0 (t=0: h1 staged in buf3)
    cell(5, zA, zB, wreg[1], lb1, 1, c1);              // L1 t1
    if (wave == 0) {                                   // output projection (one tile)
      const unsigned short* z0 = act + zA * (ROWS * LSTR) + aoffl;
      const unsigned short* z1 = act + zB * (ROWS * LSTR) + aoffl;
      f32x4 po = *reinterpret_cast<const f32x4*>(smem + BOUT_OFF + lg * 16);
      #pragma unroll
      for (int s = 0; s < 4; ++s) {
        bf16x8 z = *reinterpret_cast<const bf16x8*>(&z0[s * 32]);
        po = __builtin_amdgcn_mfma_f32_16x16x32_bf16(wov[s * 64 + lane], z, po, 0, 0, 0);
      }
      #pragma unroll
      for (int s = 0; s < 4; ++s) {
        bf16x8 z = *reinterpret_cast<const bf16x8*>(&z1[s * 32]);
        po = __builtin_amdgcn_mfma_f32_16x16x32_bf16(wov[(4 + s) * 64 + lane], z, po, 0, 0, 0);
      }
      if (lg < 3) {
        f32x4 r;
        r[0] = fsig(po[0]); r[1] = fsig(po[1]); r[2] = fsig(po[2]); r[3] = fsig(po[3]);
        *reinterpret_cast<f32x4*>(&out[(size_t)(n0 + col) * OUTSTRIDE + t * NFEAT + lg * 4]) = r;
      }
    }
  }
}

extern "C" void kernel_launch(void* const* d_in, const int* in_sizes, int n_in,
                              void* d_out, int out_size, void* d_ws, size_t ws_size,
                              hipStream_t stream) {
  const float* ench = (const float*)d_in[0];
  const float* encc = (const float*)d_in[1];
  const float* Wih0 = (const float*)d_in[2];
  const float* Whh0 = (const float*)d_in[3];
  const float* bih0 = (const float*)d_in[4];
  const float* bhh0 = (const float*)d_in[5];
  const float* Wih1 = (const float*)d_in[6];
  const float* Whh1 = (const float*)d_in[7];
  const float* bih1 = (const float*)d_in[8];
  const float* bhh1 = (const float*)d_in[9];
  const float* Wo   = (const float*)d_in[10];
  const float* bo   = (const float*)d_in[11];
  unsigned short* ws = (unsigned short*)d_ws;

  int total = WFRAG_ELEMS + WOUT_ELEMS + 1024 + 16;
  int blocks = (total + 511) / 512;
  hipLaunchKernelGGL(setup_kernel, dim3(blocks), dim3(512), 0, stream,
                     Wih0, Whh0, bih0, bhh0, Wih1, Whh1, bih1, bhh1, Wo, bo, ws);

  const unsigned short* wfrag = ws;
  const unsigned short* woutf = ws + WFRAG_ELEMS;
  const float* biasc = reinterpret_cast<const float*>(ws) + BIAS_F32OFF;
  const float* boutc = reinterpret_cast<const float*>(ws) + BOUT_F32OFF;

  hipLaunchKernelGGL(lstm_kernel, dim3(NBATCH / ROWS), dim3(512), 0, stream,
                     ench, encc, wfrag, woutf, biasc, boutc, (float*)d_out);
}